// Round 1
// baseline (471.732 us; speedup 1.0000x reference)
//
#include <hip/hip_runtime.h>
#include <math.h>

// DecoderSphere: B=16, T=65536, D=32, H=W=64.
// One thread per (b,t) point. fp32 VALU baseline (no fp32 MFMA on CDNA4).
// Weights read through wave-uniform addresses -> scalar loads (SGPR operands).

#define ND 32

__global__ __launch_bounds__(256) void decoder_sphere_kernel(
    const float* __restrict__ p,
    const float* __restrict__ c,
    const float* __restrict__ fc_p_w,
    const float* __restrict__ fc_p_b,
    const float* __restrict__ w0,
    const float* __restrict__ b0,
    const float* __restrict__ w1,
    const float* __restrict__ b1,
    const float* __restrict__ fc_out_w,
    const float* __restrict__ fc_out_b,
    float* __restrict__ out)
{
    const float PI_F = 3.1415927410125732f;

    const int g = blockIdx.x * blockDim.x + threadIdx.x;   // 0 .. B*T-1
    const int b = g >> 16;                                  // T = 65536

    // ---- load point ----
    const float px = p[3 * g + 0];
    const float py = p[3 * g + 1];
    const float pz = p[3 * g + 2];

    // ---- sphere interp indices (faithful port incl. quirks) ----
    // lat = 90 - atan2(z, sqrt(x^2+y^2)) * 180 / PI   (all f32, same op order)
    const float lat = 90.0f - (atan2f(pz, sqrtf(px * px + py * py)) * 180.0f) / PI_F;
    // mer = (360 + atan2(y, x) * 180 / PI) % 360
    const float mer = fmodf(360.0f + (atan2f(py, px) * 180.0f) / PI_F, 360.0f);

    const float xgf = floorf(mer / 5.625f);    // dmi = 360/64
    const float ygf = floorf(lat / 2.8125f);   // dli = 180/64
    const int xg = (int)xgf;                   // [0,63]
    const int yg = (int)ygf;                   // [0,64] (64 only measure-zero)

    const int xl = (xg + 63) & 63;             // (x_grid-1) mod 64, python semantics
    const int xr = (xg + 1) & 63;              // (x_grid+1) mod 64
    // y_low  = yg - 1 - floor((yg-1)/64) ; arithmetic >> is floor-div here
    const int ylo = yg - 1 - ((yg - 1) >> 6);
    // y_high = yg + 1 - floor((yg+1)/64)
    const int yhi = yg + 1 - ((yg + 1) >> 6);

    // dx/dy from the *unclamped* integer values (exact small ints in float)
    const float dx = (float)(xr - xg);         // 1 normally, -63 at wrap
    const float dy = (float)(yhi - yg);        // 1 normally, 0 at south edge

    // gather indices (JAX clamps OOB gather indices)
    const int yloi = ylo < 63 ? ylo : 63;
    const int yhii = yhi < 63 ? yhi : 63;

    const float w11 = dx * dy;
    const float w12 = (1.0f - dx) * dy;
    const float w21 = dx * (1.0f - dy);
    const float w22 = (1.0f - dx) * (1.0f - dy);

    // quirk: meridian index on grid dim 1, latitude index on dim 2
    const float* gb  = c + (size_t)b * (64 * 64 * ND);
    const float* r11 = gb + (xl * 64 + yloi) * ND;
    const float* r12 = gb + (xr * 64 + yloi) * ND;
    const float* r21 = gb + (xl * 64 + yhii) * ND;
    const float* r22 = gb + (xr * 64 + yhii) * ND;

    float cf[ND];
#pragma unroll
    for (int d = 0; d < ND; d += 4) {
        const float4 a = *(const float4*)(r11 + d);
        const float4 e = *(const float4*)(r12 + d);
        const float4 f = *(const float4*)(r21 + d);
        const float4 h4 = *(const float4*)(r22 + d);
        cf[d + 0] = w11 * a.x + w12 * e.x + w21 * f.x + w22 * h4.x;
        cf[d + 1] = w11 * a.y + w12 * e.y + w21 * f.y + w22 * h4.y;
        cf[d + 2] = w11 * a.z + w12 * e.z + w21 * f.z + w22 * h4.z;
        cf[d + 3] = w11 * a.w + w12 * e.w + w21 * f.w + w22 * h4.w;
    }

    // ---- net = p @ fc_p_w + fc_p_b ----
    float net[ND];
#pragma unroll
    for (int d = 0; d < ND; ++d) {
        net[d] = fmaf(px, fc_p_w[d],
                 fmaf(py, fc_p_w[ND + d],
                 fmaf(pz, fc_p_w[2 * ND + d], fc_p_b[d])));
    }

    // ---- 5 resnet blocks ----
    for (int i = 0; i < 5; ++i) {
        const float* W0 = w0 + i * ND * ND;
        const float* B0 = b0 + i * ND;
        const float* W1 = w1 + i * ND * ND;
        const float* B1 = b1 + i * ND;

#pragma unroll
        for (int d = 0; d < ND; ++d) net[d] += cf[d];

        float h[ND];
#pragma unroll
        for (int j = 0; j < ND; ++j) h[j] = B0[j];

#pragma unroll
        for (int d = 0; d < ND; ++d) {
            const float rn = fmaxf(net[d], 0.0f);
#pragma unroll
            for (int j = 0; j < ND; ++j)
                h[j] = fmaf(rn, W0[d * ND + j], h[j]);
        }

#pragma unroll
        for (int j = 0; j < ND; ++j) h[j] = fmaxf(h[j], 0.0f);

#pragma unroll
        for (int j = 0; j < ND; ++j) {
            const float hj = h[j];
#pragma unroll
            for (int d = 0; d < ND; ++d)
                net[d] = fmaf(hj, W1[j * ND + d], net[d]);
        }

#pragma unroll
        for (int d = 0; d < ND; ++d) net[d] += B1[d];
    }

    // ---- out = relu(net) @ fc_out_w + fc_out_b ----
    float acc = fc_out_b[0];
#pragma unroll
    for (int d = 0; d < ND; ++d)
        acc = fmaf(fmaxf(net[d], 0.0f), fc_out_w[d], acc);

    out[g] = acc;
}

extern "C" void kernel_launch(void* const* d_in, const int* in_sizes, int n_in,
                              void* d_out, int out_size, void* d_ws, size_t ws_size,
                              hipStream_t stream) {
    const float* p        = (const float*)d_in[0];
    // d_in[1] = z (unused by reference)
    const float* c        = (const float*)d_in[2];
    // d_in[3] = C_mat (unused by reference)
    const float* fc_p_w   = (const float*)d_in[4];
    const float* fc_p_b   = (const float*)d_in[5];
    const float* w0       = (const float*)d_in[6];
    const float* b0       = (const float*)d_in[7];
    const float* w1       = (const float*)d_in[8];
    const float* b1       = (const float*)d_in[9];
    const float* fc_out_w = (const float*)d_in[10];
    const float* fc_out_b = (const float*)d_in[11];
    float* out = (float*)d_out;

    const int total = 16 * 65536;
    dim3 block(256);
    dim3 grid(total / 256);
    hipLaunchKernelGGL(decoder_sphere_kernel, grid, block, 0, stream,
                       p, c, fc_p_w, fc_p_b, w0, b0, w1, b1,
                       fc_out_w, fc_out_b, out);
}